// Round 1
// baseline (335.094 us; speedup 1.0000x reference)
//
#include <hip/hip_runtime.h>
#include <hip/hip_bf16.h>
#include <stdint.h>

#define N_NODES 50000
#define N_EDGES 1000000
#define HIDDEN 128

using short8  = __attribute__((ext_vector_type(8))) short;
using floatx4 = __attribute__((ext_vector_type(4))) float;

__device__ __forceinline__ float bf2f(uint16_t u) {
    return __uint_as_float(((uint32_t)u) << 16);
}
__device__ __forceinline__ uint16_t f2bf(float f) {
    uint32_t x = __float_as_uint(f);
    return (uint16_t)((x + 0x7FFFu + ((x >> 16) & 1u)) >> 16);
}
__device__ __forceinline__ float fast_silu(float x) {
    // x * sigmoid(x); exp(-x)->inf for very negative x gives rcp(inf)=0 -> 0  (correct limit)
    float e = __expf(-x);
    return x * __builtin_amdgcn_rcpf(1.0f + e);
}

// ---------------------------------------------------------------------------
// Kernel 1: At[n][k] = sum_j h[n][j]*W1[j][k] + b1[k]   (k<128)
//           Bt[n][k] = sum_j h[n][j]*W1[128+j][k]
// bf16 MFMA 16x16x32; each wave does 16 nodes x 256 output channels.
// ---------------------------------------------------------------------------
__global__ __launch_bounds__(256) void precompute_AB(
    const float* __restrict__ h, const float* __restrict__ W1,
    const float* __restrict__ b1,
    uint16_t* __restrict__ At, uint16_t* __restrict__ Bt)
{
    __shared__ uint16_t w1t[256 * 128];  // [c][j] bf16, XOR-swizzled, 64 KB
    int t = threadIdx.x;
    for (int idx = t; idx < 256 * 128; idx += 256) {
        int c = idx >> 7, j = idx & 127;
        float v = (c < 128) ? W1[j * 128 + c] : W1[(128 + j) * 128 + (c - 128)];
        int byte_off = (c << 8) + (j << 1);
        byte_off ^= ((c & 7) << 4);
        *(uint16_t*)((char*)w1t + byte_off) = f2bf(v);
    }
    __syncthreads();

    int wave = t >> 6, lane = t & 63;
    int lrow = lane & 15, kg = lane >> 4;

    int nodeBase = blockIdx.x * 64 + wave * 16;
    int node = nodeBase + lrow;
    int nclamp = node < N_NODES ? node : N_NODES - 1;
    const float* hrow = h + (size_t)nclamp * 128;

    short8 afrag[4];
#pragma unroll
    for (int kk = 0; kk < 4; ++kk) {
        int k0 = kk * 32 + kg * 8;
        float4 f0 = *(const float4*)(hrow + k0);
        float4 f1 = *(const float4*)(hrow + k0 + 4);
        short8 a;
        a[0] = (short)f2bf(f0.x); a[1] = (short)f2bf(f0.y);
        a[2] = (short)f2bf(f0.z); a[3] = (short)f2bf(f0.w);
        a[4] = (short)f2bf(f1.x); a[5] = (short)f2bf(f1.y);
        a[6] = (short)f2bf(f1.z); a[7] = (short)f2bf(f1.w);
        afrag[kk] = a;
    }

    for (int nt = 0; nt < 16; ++nt) {
        floatx4 acc = {0.f, 0.f, 0.f, 0.f};
        int c = nt * 16 + lrow;
#pragma unroll
        for (int kk = 0; kk < 4; ++kk) {
            int byte_off = (c << 8) + ((kk * 32 + kg * 8) << 1);
            byte_off ^= ((c & 7) << 4);
            short8 b = *(const short8*)((const char*)w1t + byte_off);
            acc = __builtin_amdgcn_mfma_f32_16x16x32_bf16(afrag[kk], b, acc, 0, 0, 0);
        }
        // D layout: lane holds out[node=nodeBase+kg*4+r][c], c = nt*16 + (lane&15)
#pragma unroll
        for (int r = 0; r < 4; ++r) {
            int onode = nodeBase + kg * 4 + r;
            if (onode < N_NODES) {
                float v = acc[r];
                if (c < 128) {
                    At[(size_t)onode * 128 + c] = f2bf(v + b1[c]);
                } else {
                    Bt[(size_t)onode * 128 + (c - 128)] = f2bf(v);
                }
            }
        }
    }
}

// ---------------------------------------------------------------------------
// Kernel 2: per-edge fused layer1(silu) -> layer2 MFMA (silu) -> W3 dot ->
//           trans = coord_diff * m * edge_mask -> atomicAdd into agg[row].
// One wave = 16 edges. Grid-stride over 62500 tiles.
// ---------------------------------------------------------------------------
__global__ __launch_bounds__(256) void edge_kernel(
    const int* __restrict__ rowIdx, const int* __restrict__ colIdx,
    const float* __restrict__ edge_attr, const float* __restrict__ edge_mask,
    const float* __restrict__ coord_diff,
    const float* __restrict__ W1, const float* __restrict__ W2,
    const float* __restrict__ b2, const float* __restrict__ W3,
    const uint16_t* __restrict__ At, const uint16_t* __restrict__ Bt,
    float* __restrict__ agg)
{
    __shared__ uint16_t w2t[128 * 128];  // [n][k] bf16, XOR-swizzled, 32 KB
    __shared__ float s_w1e[128], s_b2[128], s_w3[128];
    int t = threadIdx.x;
    for (int idx = t; idx < 128 * 128; idx += 256) {
        int n = idx >> 7, k = idx & 127;
        float v = W2[k * 128 + n];
        int byte_off = (n << 8) + (k << 1);
        byte_off ^= ((n & 7) << 4);
        *(uint16_t*)((char*)w2t + byte_off) = f2bf(v);
    }
    if (t < 128) { s_w1e[t] = W1[256 * 128 + t]; s_b2[t] = b2[t]; s_w3[t] = W3[t]; }
    __syncthreads();

    int wave = t >> 6, lane = t & 63;
    int lrow = lane & 15, kg = lane >> 4;

    const int numTiles = N_EDGES / 16;           // 62500
    int wavesTotal = gridDim.x * 4;
    int waveId = blockIdx.x * 4 + wave;

    for (int tile = waveId; tile < numTiles; tile += wavesTotal) {
        int ebase = tile * 16;
        int e = ebase + lrow;
        int r = rowIdx[e], c = colIdx[e];
        float attr = edge_attr[e];
        const uint16_t* arow = At + (size_t)r * 128;
        const uint16_t* brow = Bt + (size_t)c * 128;

        // Layer 1: build A-fragments in registers.
        // A-frag layout: lane l holds X[row=l&15][k = kk*32 + (l>>4)*8 + j]
        short8 afrag[4];
#pragma unroll
        for (int kk = 0; kk < 4; ++kk) {
            int k0 = kk * 32 + kg * 8;
            short8 av = *(const short8*)(arow + k0);
            short8 bv = *(const short8*)(brow + k0);
            short8 u;
#pragma unroll
            for (int j = 0; j < 8; ++j) {
                float x = bf2f((uint16_t)av[j]) + bf2f((uint16_t)bv[j])
                        + attr * s_w1e[k0 + j];
                u[j] = (short)f2bf(fast_silu(x));
            }
            afrag[kk] = u;
        }

        // Layer 2 + fused silu + W3 dot
        float pm0 = 0.f, pm1 = 0.f, pm2 = 0.f, pm3 = 0.f;
#pragma unroll
        for (int nt = 0; nt < 8; ++nt) {
            floatx4 acc = {0.f, 0.f, 0.f, 0.f};
            int n = nt * 16 + lrow;
#pragma unroll
            for (int kk = 0; kk < 4; ++kk) {
                int byte_off = (n << 8) + ((kk * 32 + kg * 8) << 1);
                byte_off ^= ((n & 7) << 4);
                short8 b = *(const short8*)((const char*)w2t + byte_off);
                acc = __builtin_amdgcn_mfma_f32_16x16x32_bf16(afrag[kk], b, acc, 0, 0, 0);
            }
            float w3v = s_w3[n], b2v = s_b2[n];
            pm0 += fast_silu(acc[0] + b2v) * w3v;
            pm1 += fast_silu(acc[1] + b2v) * w3v;
            pm2 += fast_silu(acc[2] + b2v) * w3v;
            pm3 += fast_silu(acc[3] + b2v) * w3v;
        }

        // Reduce across the 16 lanes of each row-group (they hold different channels)
#pragma unroll
        for (int m = 1; m < 16; m <<= 1) {
            pm0 += __shfl_xor(pm0, m, 64);
            pm1 += __shfl_xor(pm1, m, 64);
            pm2 += __shfl_xor(pm2, m, 64);
            pm3 += __shfl_xor(pm3, m, 64);
        }
        // group kg now holds m for edges ebase + kg*4 + {0..3} in pm0..pm3

        if (lrow < 12) {
            int rsel = lrow / 3;
            int dim = lrow - rsel * 3;
            float mval = (rsel == 0) ? pm0 : (rsel == 1) ? pm1 : (rsel == 2) ? pm2 : pm3;
            int eg = ebase + kg * 4 + rsel;
            float val = coord_diff[eg * 3 + dim] * mval * edge_mask[eg];
            int rnode = rowIdx[eg];
            atomicAdd(&agg[rnode * 3 + dim], val);
        }
    }
}

// ---------------------------------------------------------------------------
// Kernel 3: out = (coord + agg/100) * node_mask
// ---------------------------------------------------------------------------
__global__ __launch_bounds__(256) void finalize_kernel(
    const float* __restrict__ coord, const float* __restrict__ agg,
    const float* __restrict__ node_mask, float* __restrict__ out)
{
    int i = blockIdx.x * 256 + threadIdx.x;
    if (i < N_NODES * 3) {
        out[i] = (coord[i] + agg[i] * 0.01f) * node_mask[i / 3];
    }
}

extern "C" void kernel_launch(void* const* d_in, const int* in_sizes, int n_in,
                              void* d_out, int out_size, void* d_ws, size_t ws_size,
                              hipStream_t stream) {
    const float* h          = (const float*)d_in[0];
    const float* coord      = (const float*)d_in[1];
    const int*   eidx       = (const int*)d_in[2];   // [2][N_EDGES] int32
    const float* coord_diff = (const float*)d_in[3];
    const float* edge_attr  = (const float*)d_in[4];
    const float* node_mask  = (const float*)d_in[5];
    const float* edge_mask  = (const float*)d_in[6];
    const float* W1 = (const float*)d_in[7];
    const float* b1 = (const float*)d_in[8];
    const float* W2 = (const float*)d_in[9];
    const float* b2 = (const float*)d_in[10];
    const float* W3 = (const float*)d_in[11];
    float* out = (float*)d_out;

    uint16_t* At = (uint16_t*)d_ws;                        // 12.8 MB
    uint16_t* Bt = At + (size_t)N_NODES * 128;             // 12.8 MB
    float*   agg = (float*)(Bt + (size_t)N_NODES * 128);   // 600 KB

    hipMemsetAsync(agg, 0, N_NODES * 3 * sizeof(float), stream);

    precompute_AB<<<(N_NODES + 63) / 64, 256, 0, stream>>>(h, W1, b1, At, Bt);

    edge_kernel<<<2048, 256, 0, stream>>>(eidx, eidx + N_EDGES, edge_attr, edge_mask,
                                          coord_diff, W1, W2, b2, W3, At, Bt, agg);

    finalize_kernel<<<(N_NODES * 3 + 255) / 256, 256, 0, stream>>>(coord, agg, node_mask, out);
}